// Round 1
// baseline (831.572 us; speedup 1.0000x reference)
//
#include <hip/hip_runtime.h>

#define DIM 64

// deg[i] = 1.0 (self-loop)
__global__ void init_deg_kernel(float* __restrict__ deg, int n) {
    int i = blockIdx.x * blockDim.x + threadIdx.x;
    if (i < n) deg[i] = 1.0f;
}

// deg[col[e]] += 1
__global__ void count_deg_kernel(const int* __restrict__ ei, float* __restrict__ deg, int E_) {
    int e = blockIdx.x * blockDim.x + threadIdx.x;
    if (e < E_) atomicAdd(&deg[ei[E_ + e]], 1.0f);
}

// deg -> dinv = rsqrt(deg)   (deg >= 1 always, no zero check needed)
__global__ void rsqrt_kernel(float* __restrict__ deg, int n) {
    int i = blockIdx.x * blockDim.x + threadIdx.x;
    if (i < n) deg[i] = rsqrtf(deg[i]);
}

// h = x @ W ; out_init = b + h * dinv^2   (self-loop contribution fused)
// x row r comes from xa[r] if r < split, else xb[r - split]  (handles the concat)
__global__ __launch_bounds__(256) void gemm_fused_kernel(
    const float* __restrict__ xa, const float* __restrict__ xb, int split,
    const float* __restrict__ W, const float* __restrict__ b,
    const float* __restrict__ dinv, float* __restrict__ h,
    float* __restrict__ out_init, int n) {
    __shared__ float Ws[DIM * DIM];   // 16 KB
    __shared__ float xs[16 * DIM];    // 4 KB

    // load W (4096 floats = 1024 float4, 256 threads x 4)
    const float4* W4 = (const float4*)W;
    float4* Ws4 = (float4*)Ws;
#pragma unroll
    for (int i = 0; i < 4; ++i)
        Ws4[threadIdx.x + i * 256] = W4[threadIdx.x + i * 256];

    int row0 = blockIdx.x * 16;
    {
        // 16 rows x 64 floats = 256 float4, one per thread
        int i = threadIdx.x;
        int r = row0 + (i >> 4);
        int c4 = i & 15;
        float4 v = make_float4(0.f, 0.f, 0.f, 0.f);
        if (r < n) {
            const float* src = (r < split) ? (xa + (size_t)r * DIM)
                                           : (xb + (size_t)(r - split) * DIM);
            v = ((const float4*)src)[c4];
        }
        ((float4*)xs)[i] = v;
    }
    __syncthreads();

    int col = threadIdx.x & 63;   // output column for this lane
    int r0 = threadIdx.x >> 6;    // wave id 0..3
    float bc = b[col];
#pragma unroll
    for (int rr = r0; rr < 16; rr += 4) {
        int r = row0 + rr;
        if (r >= n) continue;
        float acc = 0.f;
#pragma unroll
        for (int k = 0; k < DIM; ++k)
            acc = fmaf(xs[rr * DIM + k], Ws[k * DIM + col], acc);  // xs broadcast, Ws 2-way (free)
        h[(size_t)r * DIM + col] = acc;
        float di = dinv[r];
        out_init[(size_t)r * DIM + col] = fmaf(acc, di * di, bc);
    }
}

// one wave per edge: out[col] += h[row] * dinv[row] * dinv[col]
__global__ __launch_bounds__(256) void agg_kernel(
    const int* __restrict__ ei, const float* __restrict__ dinv,
    const float* __restrict__ h, float* __restrict__ out, int E_) {
    int e = blockIdx.x * 4 + (threadIdx.x >> 6);
    if (e >= E_) return;
    int lane = threadIdx.x & 63;
    int r = ei[e];        // source (row)
    int c = ei[E_ + e];   // destination (col)
    float w = dinv[r] * dinv[c];
    float v = h[(size_t)r * DIM + lane] * w;
    atomicAdd(&out[(size_t)c * DIM + lane], v);
}

extern "C" void kernel_launch(void* const* d_in, const int* in_sizes, int n_in,
                              void* d_out, int out_size, void* d_ws, size_t ws_size,
                              hipStream_t stream) {
    const int* ei        = (const int*)d_in[0];
    const float* user_emb = (const float*)d_in[1];
    const float* item_emb = (const float*)d_in[2];
    const float* W1 = (const float*)d_in[3];
    const float* b1 = (const float*)d_in[4];
    const float* W2 = (const float*)d_in[5];
    const float* b2 = (const float*)d_in[6];
    float* out = (float*)d_out;

    const int E_ = in_sizes[0] / 2;
    const int NU = in_sizes[1] / DIM;
    const int NI = in_sizes[2] / DIM;
    const int N_ = NU + NI;

    // workspace layout: dinv [N], h [N*64], t1 [N*64]  => ~103 MB
    float* deg = (float*)d_ws;              // becomes dinv in place
    float* h   = deg + N_;
    float* t1  = h + (size_t)N_ * DIM;

    init_deg_kernel<<<(N_ + 255) / 256, 256, 0, stream>>>(deg, N_);
    count_deg_kernel<<<(E_ + 255) / 256, 256, 0, stream>>>(ei, deg, E_);
    rsqrt_kernel<<<(N_ + 255) / 256, 256, 0, stream>>>(deg, N_);

    int gblocks = (N_ + 15) / 16;
    // layer 1: h = concat(user,item) @ W1 ; t1 = b1 + h*dinv^2 ; then scatter
    gemm_fused_kernel<<<gblocks, 256, 0, stream>>>(user_emb, item_emb, NU,
                                                   W1, b1, deg, h, t1, N_);
    agg_kernel<<<(E_ + 3) / 4, 256, 0, stream>>>(ei, deg, h, t1, E_);
    // layer 2: h = t1 @ W2 ; out = b2 + h*dinv^2 ; then scatter into d_out
    gemm_fused_kernel<<<gblocks, 256, 0, stream>>>(user_emb, t1, 0,
                                                   W2, b2, deg, h, out, N_);
    agg_kernel<<<(E_ + 3) / 4, 256, 0, stream>>>(ei, deg, h, out, E_);
}

// Round 2
// 680.989 us; speedup vs baseline: 1.2211x; 1.2211x over previous
//
#include <hip/hip_runtime.h>

#define DIM 64
#define ROWS_PER_WAVE 32

// ---------- CSR build ----------

__global__ void zero_cnt_kernel(int* __restrict__ cnt, int n) {
    int i = blockIdx.x * blockDim.x + threadIdx.x;
    if (i < n) cnt[i] = 0;
}

__global__ void count_kernel(const int* __restrict__ ei, int* __restrict__ cnt, int E_) {
    int e = blockIdx.x * blockDim.x + threadIdx.x;
    if (e < E_) atomicAdd(&cnt[ei[E_ + e]], 1);
}

// per-block exclusive scan of cnt -> rowptr (block-local), block totals -> partial
__global__ __launch_bounds__(256) void scanA_kernel(const int* __restrict__ cnt,
                                                    int* __restrict__ rowptr,
                                                    int* __restrict__ partial, int n) {
    __shared__ int sm[256];
    int tid = threadIdx.x;
    int i = blockIdx.x * 256 + tid;
    int v = (i < n) ? cnt[i] : 0;
    sm[tid] = v;
    __syncthreads();
    for (int off = 1; off < 256; off <<= 1) {
        int t = 0;
        if (tid >= off) t = sm[tid - off];
        __syncthreads();
        if (tid >= off) sm[tid] += t;
        __syncthreads();
    }
    if (i < n) rowptr[i] = sm[tid] - v;           // exclusive
    if (tid == 255) partial[blockIdx.x] = sm[255]; // block total
}

// exclusive scan of partial[nb] in place (nb <= 1024)
__global__ __launch_bounds__(1024) void scanB_kernel(int* __restrict__ partial, int nb) {
    __shared__ int sm[1024];
    int tid = threadIdx.x;
    int v = (tid < nb) ? partial[tid] : 0;
    sm[tid] = v;
    __syncthreads();
    for (int off = 1; off < 1024; off <<= 1) {
        int t = 0;
        if (tid >= off) t = sm[tid - off];
        __syncthreads();
        if (tid >= off) sm[tid] += t;
        __syncthreads();
    }
    if (tid < nb) partial[tid] = sm[tid] - v;
}

// finalize rowptr, init cursor, compute dinv = rsqrt(1 + indeg)
__global__ void scanC_kernel(const int* __restrict__ cnt, int* __restrict__ rowptr,
                             int* __restrict__ cursor, float* __restrict__ dinv,
                             const int* __restrict__ partial, int n, int E_) {
    int i = blockIdx.x * blockDim.x + threadIdx.x;
    if (i < n) {
        int val = rowptr[i] + partial[i >> 8];
        rowptr[i] = val;
        cursor[i] = val;
        dinv[i] = rsqrtf((float)(1 + cnt[i]));
    }
    if (i == 0) rowptr[n] = E_;
}

// scatter edges into CSR buckets; precompute per-edge weight
__global__ void fill_kernel(const int* __restrict__ ei, const float* __restrict__ dinv,
                            int* __restrict__ cursor, int* __restrict__ srcs,
                            float* __restrict__ wts, int E_) {
    int e = blockIdx.x * blockDim.x + threadIdx.x;
    if (e >= E_) return;
    int s = ei[e], d = ei[E_ + e];
    int pos = atomicAdd(&cursor[d], 1);
    srcs[pos] = s;
    wts[pos] = dinv[s] * dinv[d];
}

// ---------- layer kernels ----------

// h = x @ W ; out_init = b + h * dinv^2   (self-loop fused)
// No LDS: W column in 64 VGPRs/lane; x-row loads are wave-uniform -> s_load.
__global__ __launch_bounds__(256) void gemm_fused_kernel(
    const float* __restrict__ xa, const float* __restrict__ xb, int split,
    const float* __restrict__ W, const float* __restrict__ b,
    const float* __restrict__ dinv, float* __restrict__ h,
    float* __restrict__ oinit, int n) {
    int lane = threadIdx.x & 63;
    int wv = __builtin_amdgcn_readfirstlane(threadIdx.x >> 6);
    int wave = blockIdx.x * 4 + wv;

    float wreg[DIM];
#pragma unroll
    for (int k = 0; k < DIM; ++k) wreg[k] = W[k * DIM + lane];  // coalesced, L1-hot
    float bc = b[lane];

    int row0 = wave * ROWS_PER_WAVE;
    for (int rr = 0; rr < ROWS_PER_WAVE; ++rr) {
        int row = row0 + rr;
        if (row >= n) return;
        const float* xr = (row < split) ? (xa + (size_t)row * DIM)
                                        : (xb + (size_t)(row - split) * DIM);
        float acc = 0.f;
#pragma unroll
        for (int k = 0; k < DIM; ++k)
            acc = fmaf(xr[k], wreg[k], acc);   // sgpr * vgpr fma, no LDS
        h[(size_t)row * DIM + lane] = acc;
        float di = dinv[row];
        oinit[(size_t)row * DIM + lane] = fmaf(acc, di * di, bc);
    }
}

// one wave per destination node: register accumulate over its CSR bucket
__global__ __launch_bounds__(256) void agg_kernel(
    const int* __restrict__ rowptr, const int* __restrict__ srcs,
    const float* __restrict__ wts, const float* __restrict__ h,
    float* __restrict__ io, int n) {
    int lane = threadIdx.x & 63;
    int wv = __builtin_amdgcn_readfirstlane(threadIdx.x >> 6);
    int node = blockIdx.x * 4 + wv;
    if (node >= n) return;
    int beg = rowptr[node];
    int end = rowptr[node + 1];
    size_t o = (size_t)node * DIM + lane;
    float acc = io[o];   // b + self-loop term, written by gemm epilogue
    for (int i = beg; i < end; ++i) {
        int s = srcs[i];      // wave-uniform -> s_load
        float w = wts[i];     // wave-uniform -> s_load
        acc = fmaf(h[(size_t)s * DIM + lane], w, acc);  // 256B coalesced gather
    }
    io[o] = acc;
}

extern "C" void kernel_launch(void* const* d_in, const int* in_sizes, int n_in,
                              void* d_out, int out_size, void* d_ws, size_t ws_size,
                              hipStream_t stream) {
    const int* ei         = (const int*)d_in[0];
    const float* user_emb = (const float*)d_in[1];
    const float* item_emb = (const float*)d_in[2];
    const float* W1 = (const float*)d_in[3];
    const float* b1 = (const float*)d_in[4];
    const float* W2 = (const float*)d_in[5];
    const float* b2 = (const float*)d_in[6];
    float* out = (float*)d_out;

    const int E_ = in_sizes[0] / 2;
    const int NU = in_sizes[1] / DIM;
    const int NI = in_sizes[2] / DIM;
    const int N_ = NU + NI;

    // workspace layout
    float* dinv  = (float*)d_ws;                 // N
    int* cnt     = (int*)(dinv + N_);            // N
    int* rowptr  = cnt + N_;                     // N+1
    int* cursor  = rowptr + N_ + 1;              // N
    int* partial = cursor + N_;                  // 1024
    int* srcs    = partial + 1024;               // E
    float* wts   = (float*)(srcs + E_);          // E
    float* h     = wts + E_;                     // N*64
    float* t1    = h + (size_t)N_ * DIM;         // N*64

    int nb = (N_ + 255) / 256;

    zero_cnt_kernel<<<(N_ + 255) / 256, 256, 0, stream>>>(cnt, N_);
    count_kernel<<<(E_ + 255) / 256, 256, 0, stream>>>(ei, cnt, E_);
    scanA_kernel<<<nb, 256, 0, stream>>>(cnt, rowptr, partial, N_);
    scanB_kernel<<<1, 1024, 0, stream>>>(partial, nb);
    scanC_kernel<<<(N_ + 255) / 256, 256, 0, stream>>>(cnt, rowptr, cursor, dinv,
                                                       partial, N_, E_);
    fill_kernel<<<(E_ + 255) / 256, 256, 0, stream>>>(ei, dinv, cursor, srcs, wts, E_);

    int waves = (N_ + ROWS_PER_WAVE - 1) / ROWS_PER_WAVE;
    int gblocks = (waves + 3) / 4;
    int ablocks = (N_ + 3) / 4;

    // layer 1
    gemm_fused_kernel<<<gblocks, 256, 0, stream>>>(user_emb, item_emb, NU,
                                                   W1, b1, dinv, h, t1, N_);
    agg_kernel<<<ablocks, 256, 0, stream>>>(rowptr, srcs, wts, h, t1, N_);
    // layer 2
    gemm_fused_kernel<<<gblocks, 256, 0, stream>>>(t1, t1, N_,
                                                   W2, b2, dinv, h, out, N_);
    agg_kernel<<<ablocks, 256, 0, stream>>>(rowptr, srcs, wts, h, out, N_);
}

// Round 3
// 543.061 us; speedup vs baseline: 1.5313x; 1.2540x over previous
//
#include <hip/hip_runtime.h>

#define DIM 64

__device__ __forceinline__ float bcast_lane(float v, int lane) {
    return __int_as_float(__builtin_amdgcn_readlane(__float_as_int(v), lane));
}

// ---------- CSR build ----------

__global__ void zero_cnt_kernel(int* __restrict__ cnt, int n) {
    int i = blockIdx.x * blockDim.x + threadIdx.x;
    if (i < n) cnt[i] = 0;
}

__global__ void count_kernel(const int* __restrict__ ei, int* __restrict__ cnt, int E_) {
    int e = blockIdx.x * blockDim.x + threadIdx.x;
    if (e < E_) atomicAdd(&cnt[ei[E_ + e]], 1);
}

__global__ __launch_bounds__(256) void scanA_kernel(const int* __restrict__ cnt,
                                                    int* __restrict__ rowptr,
                                                    int* __restrict__ partial, int n) {
    __shared__ int sm[256];
    int tid = threadIdx.x;
    int i = blockIdx.x * 256 + tid;
    int v = (i < n) ? cnt[i] : 0;
    sm[tid] = v;
    __syncthreads();
    for (int off = 1; off < 256; off <<= 1) {
        int t = 0;
        if (tid >= off) t = sm[tid - off];
        __syncthreads();
        if (tid >= off) sm[tid] += t;
        __syncthreads();
    }
    if (i < n) rowptr[i] = sm[tid] - v;
    if (tid == 255) partial[blockIdx.x] = sm[255];
}

__global__ __launch_bounds__(1024) void scanB_kernel(int* __restrict__ partial, int nb) {
    __shared__ int sm[1024];
    int tid = threadIdx.x;
    int v = (tid < nb) ? partial[tid] : 0;
    sm[tid] = v;
    __syncthreads();
    for (int off = 1; off < 1024; off <<= 1) {
        int t = 0;
        if (tid >= off) t = sm[tid - off];
        __syncthreads();
        if (tid >= off) sm[tid] += t;
        __syncthreads();
    }
    if (tid < nb) partial[tid] = sm[tid] - v;
}

__global__ void scanC_kernel(const int* __restrict__ cnt, int* __restrict__ rowptr,
                             int* __restrict__ cursor, float* __restrict__ dinv,
                             const int* __restrict__ partial, int n, int E_) {
    int i = blockIdx.x * blockDim.x + threadIdx.x;
    if (i < n) {
        int val = rowptr[i] + partial[i >> 8];
        rowptr[i] = val;
        cursor[i] = val;
        dinv[i] = rsqrtf((float)(1 + cnt[i]));
    }
    if (i == 0) rowptr[n] = E_;
}

__global__ void fill_kernel(const int* __restrict__ ei, const float* __restrict__ dinv,
                            int* __restrict__ cursor, int* __restrict__ srcs,
                            float* __restrict__ wts, int E_) {
    int e = blockIdx.x * blockDim.x + threadIdx.x;
    if (e >= E_) return;
    int s = ei[e], d = ei[E_ + e];
    int pos = atomicAdd(&cursor[d], 1);
    srcs[pos] = s;
    wts[pos] = dinv[s] * dinv[d];
}

// ---------- layer kernels ----------

// h = x @ W ; oinit = b + h*dinv^2.  Wave processes 32 rows in 4-row groups:
// one float4/lane coalesced load covers 4 rows; v_readlane broadcasts x[r][k]
// (constant lane index under full unroll) into v_fmac with W in 64 VGPRs/lane.
__global__ __launch_bounds__(256) void gemm_fused_kernel(
    const float* __restrict__ xa, const float* __restrict__ xb, int split,
    const float* __restrict__ W, const float* __restrict__ b,
    const float* __restrict__ dinv, float* __restrict__ h,
    float* __restrict__ oinit, int n) {
    int lane = threadIdx.x & 63;
    int wave = blockIdx.x * 4 + (threadIdx.x >> 6);
    int row0 = wave * 32;
    if (row0 >= n) return;

    float wreg[DIM];
#pragma unroll
    for (int k = 0; k < DIM; ++k) wreg[k] = W[k * DIM + lane];  // coalesced, L1-hot
    float bc = b[lane];

    // group g covers rows row0+4g .. row0+4g+3 (n is a multiple of 4)
    const float* base0 = (row0 < split) ? (xa + (size_t)row0 * DIM)
                                        : (xb + (size_t)(row0 - split) * DIM);
    float4 xv = ((const float4*)base0)[lane];

#pragma unroll 1
    for (int g = 0; g < 8; ++g) {
        int r4 = row0 + g * 4;
        if (r4 >= n) break;
        // prefetch next group
        float4 nxt = xv;
        int rn = r4 + 4;
        if (g < 7 && rn < n) {
            const float* bn = (rn < split) ? (xa + (size_t)rn * DIM)
                                           : (xb + (size_t)(rn - split) * DIM);
            nxt = ((const float4*)bn)[lane];
        }
#pragma unroll
        for (int j = 0; j < 4; ++j) {
            int row = r4 + j;
            if (row >= n) break;
            float acc = 0.f;
#pragma unroll
            for (int k = 0; k < DIM; ++k) {
                float xe = ((k & 3) == 0) ? xv.x : ((k & 3) == 1) ? xv.y
                         : ((k & 3) == 2) ? xv.z : xv.w;
                float s = bcast_lane(xe, j * 16 + (k >> 2));
                acc = fmaf(s, wreg[k], acc);
            }
            h[(size_t)row * DIM + lane] = acc;
            float di = dinv[row];
            oinit[(size_t)row * DIM + lane] = fmaf(acc, di * di, bc);
        }
        xv = nxt;
    }
}

// one wave per destination node; unroll-4 so gathers overlap
__global__ __launch_bounds__(256) void agg_kernel(
    const int* __restrict__ rowptr, const int* __restrict__ srcs,
    const float* __restrict__ wts, const float* __restrict__ h,
    float* __restrict__ io, int n) {
    int lane = threadIdx.x & 63;
    int node = blockIdx.x * 4 + (threadIdx.x >> 6);
    if (node >= n) return;
    int beg = rowptr[node];
    int end = rowptr[node + 1];
    size_t o = (size_t)node * DIM + lane;
    float acc = io[o];   // b + self-loop term from gemm epilogue
    float a0 = 0.f, a1 = 0.f, a2 = 0.f, a3 = 0.f;
    int i = beg;
    for (; i + 4 <= end; i += 4) {
        int s0 = srcs[i], s1 = srcs[i + 1], s2 = srcs[i + 2], s3 = srcs[i + 3];
        float w0 = wts[i], w1 = wts[i + 1], w2 = wts[i + 2], w3 = wts[i + 3];
        a0 = fmaf(h[(size_t)s0 * DIM + lane], w0, a0);
        a1 = fmaf(h[(size_t)s1 * DIM + lane], w1, a1);
        a2 = fmaf(h[(size_t)s2 * DIM + lane], w2, a2);
        a3 = fmaf(h[(size_t)s3 * DIM + lane], w3, a3);
    }
    for (; i < end; ++i)
        acc = fmaf(h[(size_t)srcs[i] * DIM + lane], wts[i], acc);
    acc += (a0 + a1) + (a2 + a3);
    io[o] = acc;
}

extern "C" void kernel_launch(void* const* d_in, const int* in_sizes, int n_in,
                              void* d_out, int out_size, void* d_ws, size_t ws_size,
                              hipStream_t stream) {
    const int* ei         = (const int*)d_in[0];
    const float* user_emb = (const float*)d_in[1];
    const float* item_emb = (const float*)d_in[2];
    const float* W1 = (const float*)d_in[3];
    const float* b1 = (const float*)d_in[4];
    const float* W2 = (const float*)d_in[5];
    const float* b2 = (const float*)d_in[6];
    float* out = (float*)d_out;

    const int E_ = in_sizes[0] / 2;
    const int NU = in_sizes[1] / DIM;
    const int NI = in_sizes[2] / DIM;
    const int N_ = NU + NI;

    float* dinv  = (float*)d_ws;                 // N
    int* cnt     = (int*)(dinv + N_);            // N
    int* rowptr  = cnt + N_;                     // N+1
    int* cursor  = rowptr + N_ + 1;              // N
    int* partial = cursor + N_;                  // 1024
    int* srcs    = partial + 1024;               // E
    float* wts   = (float*)(srcs + E_);          // E
    float* h     = wts + E_;                     // N*64
    float* t1    = h + (size_t)N_ * DIM;         // N*64

    int nb = (N_ + 255) / 256;

    zero_cnt_kernel<<<(N_ + 255) / 256, 256, 0, stream>>>(cnt, N_);
    count_kernel<<<(E_ + 255) / 256, 256, 0, stream>>>(ei, cnt, E_);
    scanA_kernel<<<nb, 256, 0, stream>>>(cnt, rowptr, partial, N_);
    scanB_kernel<<<1, 1024, 0, stream>>>(partial, nb);
    scanC_kernel<<<(N_ + 255) / 256, 256, 0, stream>>>(cnt, rowptr, cursor, dinv,
                                                       partial, N_, E_);
    fill_kernel<<<(E_ + 255) / 256, 256, 0, stream>>>(ei, dinv, cursor, srcs, wts, E_);

    int waves = (N_ + 31) / 32;
    int gblocks = (waves + 3) / 4;
    int ablocks = (N_ + 3) / 4;

    // layer 1
    gemm_fused_kernel<<<gblocks, 256, 0, stream>>>(user_emb, item_emb, NU,
                                                   W1, b1, dinv, h, t1, N_);
    agg_kernel<<<ablocks, 256, 0, stream>>>(rowptr, srcs, wts, h, t1, N_);
    // layer 2
    gemm_fused_kernel<<<gblocks, 256, 0, stream>>>(t1, t1, N_,
                                                   W2, b2, dinv, h, out, N_);
    agg_kernel<<<ablocks, 256, 0, stream>>>(rowptr, srcs, wts, h, out, N_);
}

// Round 4
// 471.657 us; speedup vs baseline: 1.7631x; 1.1514x over previous
//
#include <hip/hip_runtime.h>
#include <hip/hip_bf16.h>

#define DIM 64

__device__ __forceinline__ float bcast_lane(float v, int lane) {
    return __int_as_float(__builtin_amdgcn_readlane(__float_as_int(v), lane));
}

// ---------- CSR build ----------

__global__ void zero_cnt_kernel(int* __restrict__ cnt, int n) {
    int i = blockIdx.x * blockDim.x + threadIdx.x;
    if (i < n) cnt[i] = 0;
}

__global__ void count_kernel(const int* __restrict__ ei, int* __restrict__ cnt, int E_) {
    int e = blockIdx.x * blockDim.x + threadIdx.x;
    if (e < E_) atomicAdd(&cnt[ei[E_ + e]], 1);
}

__global__ __launch_bounds__(256) void scanA_kernel(const int* __restrict__ cnt,
                                                    int* __restrict__ rowptr,
                                                    int* __restrict__ partial, int n) {
    __shared__ int sm[256];
    int tid = threadIdx.x;
    int i = blockIdx.x * 256 + tid;
    int v = (i < n) ? cnt[i] : 0;
    sm[tid] = v;
    __syncthreads();
    for (int off = 1; off < 256; off <<= 1) {
        int t = 0;
        if (tid >= off) t = sm[tid - off];
        __syncthreads();
        if (tid >= off) sm[tid] += t;
        __syncthreads();
    }
    if (i < n) rowptr[i] = sm[tid] - v;
    if (tid == 255) partial[blockIdx.x] = sm[255];
}

__global__ __launch_bounds__(1024) void scanB_kernel(int* __restrict__ partial, int nb) {
    __shared__ int sm[1024];
    int tid = threadIdx.x;
    int v = (tid < nb) ? partial[tid] : 0;
    sm[tid] = v;
    __syncthreads();
    for (int off = 1; off < 1024; off <<= 1) {
        int t = 0;
        if (tid >= off) t = sm[tid - off];
        __syncthreads();
        if (tid >= off) sm[tid] += t;
        __syncthreads();
    }
    if (tid < nb) partial[tid] = sm[tid] - v;
}

__global__ void scanC_kernel(const int* __restrict__ cnt, int* __restrict__ rowptr,
                             int* __restrict__ cursor, float* __restrict__ dinv,
                             const int* __restrict__ partial, int n, int E_) {
    int i = blockIdx.x * blockDim.x + threadIdx.x;
    if (i < n) {
        int val = rowptr[i] + partial[i >> 8];
        rowptr[i] = val;
        cursor[i] = val;
        dinv[i] = rsqrtf((float)(1 + cnt[i]));
    }
    if (i == 0) rowptr[n] = E_;
}

// scatter edges into CSR buckets; (src, weight) packed -> ONE random line/edge
__global__ void fill_kernel(const int* __restrict__ ei, const float* __restrict__ dinv,
                            int* __restrict__ cursor, int2* __restrict__ edges, int E_) {
    int e = blockIdx.x * blockDim.x + threadIdx.x;
    if (e >= E_) return;
    int s = ei[e], d = ei[E_ + e];
    int pos = atomicAdd(&cursor[d], 1);
    edges[pos] = make_int2(s, __float_as_int(dinv[s] * dinv[d]));
}

// ---------- layer kernels ----------

// h(bf16) = x @ W ; oinit(f32) = b + h*dinv^2.
__global__ __launch_bounds__(256) void gemm_fused_kernel(
    const float* __restrict__ xa, const float* __restrict__ xb, int split,
    const float* __restrict__ W, const float* __restrict__ b,
    const float* __restrict__ dinv, __hip_bfloat16* __restrict__ h,
    float* __restrict__ oinit, int n) {
    int lane = threadIdx.x & 63;
    int wave = blockIdx.x * 4 + (threadIdx.x >> 6);
    int row0 = wave * 32;
    if (row0 >= n) return;

    float wreg[DIM];
#pragma unroll
    for (int k = 0; k < DIM; ++k) wreg[k] = W[k * DIM + lane];  // coalesced, L1-hot
    float bc = b[lane];

    const float* base0 = (row0 < split) ? (xa + (size_t)row0 * DIM)
                                        : (xb + (size_t)(row0 - split) * DIM);
    float4 xv = ((const float4*)base0)[lane];

#pragma unroll 1
    for (int g = 0; g < 8; ++g) {
        int r4 = row0 + g * 4;
        if (r4 >= n) break;
        float4 nxt = xv;
        int rn = r4 + 4;
        if (g < 7 && rn < n) {
            const float* bn = (rn < split) ? (xa + (size_t)rn * DIM)
                                           : (xb + (size_t)(rn - split) * DIM);
            nxt = ((const float4*)bn)[lane];
        }
#pragma unroll
        for (int j = 0; j < 4; ++j) {
            int row = r4 + j;
            if (row >= n) break;
            float acc = 0.f;
#pragma unroll
            for (int k = 0; k < DIM; ++k) {
                float xe = ((k & 3) == 0) ? xv.x : ((k & 3) == 1) ? xv.y
                         : ((k & 3) == 2) ? xv.z : xv.w;
                float s = bcast_lane(xe, j * 16 + (k >> 2));
                acc = fmaf(s, wreg[k], acc);
            }
            h[(size_t)row * DIM + lane] = __float2bfloat16(acc);
            float di = dinv[row];
            oinit[(size_t)row * DIM + lane] = fmaf(acc, di * di, bc);
        }
        xv = nxt;
    }
}

// one wave per destination node; packed edge stream (scalarized), bf16 gather
__global__ __launch_bounds__(256) void agg_kernel(
    const int* __restrict__ rowptr, const int2* __restrict__ edges,
    const __hip_bfloat16* __restrict__ h, float* __restrict__ io, int n) {
    int lane = threadIdx.x & 63;
    int node = __builtin_amdgcn_readfirstlane(blockIdx.x * 4 + (threadIdx.x >> 6));
    if (node >= n) return;
    int beg = rowptr[node];
    int end = rowptr[node + 1];
    size_t o = (size_t)node * DIM + lane;
    float acc = io[o];   // b + self-loop term from gemm epilogue
    float a0 = 0.f, a1 = 0.f, a2 = 0.f, a3 = 0.f;
    int i = beg;
    for (; i + 4 <= end; i += 4) {
        int2 e0 = edges[i], e1 = edges[i + 1], e2 = edges[i + 2], e3 = edges[i + 3];
        float h0 = __bfloat162float(h[(size_t)e0.x * DIM + lane]);
        float h1 = __bfloat162float(h[(size_t)e1.x * DIM + lane]);
        float h2 = __bfloat162float(h[(size_t)e2.x * DIM + lane]);
        float h3 = __bfloat162float(h[(size_t)e3.x * DIM + lane]);
        a0 = fmaf(h0, __int_as_float(e0.y), a0);
        a1 = fmaf(h1, __int_as_float(e1.y), a1);
        a2 = fmaf(h2, __int_as_float(e2.y), a2);
        a3 = fmaf(h3, __int_as_float(e3.y), a3);
    }
    for (; i < end; ++i) {
        int2 e = edges[i];
        acc = fmaf(__bfloat162float(h[(size_t)e.x * DIM + lane]),
                   __int_as_float(e.y), acc);
    }
    acc += (a0 + a1) + (a2 + a3);
    io[o] = acc;
}

static inline size_t align16(size_t x) { return (x + 15) & ~(size_t)15; }

extern "C" void kernel_launch(void* const* d_in, const int* in_sizes, int n_in,
                              void* d_out, int out_size, void* d_ws, size_t ws_size,
                              hipStream_t stream) {
    const int* ei         = (const int*)d_in[0];
    const float* user_emb = (const float*)d_in[1];
    const float* item_emb = (const float*)d_in[2];
    const float* W1 = (const float*)d_in[3];
    const float* b1 = (const float*)d_in[4];
    const float* W2 = (const float*)d_in[5];
    const float* b2 = (const float*)d_in[6];
    float* out = (float*)d_out;

    const int E_ = in_sizes[0] / 2;
    const int NU = in_sizes[1] / DIM;
    const int NI = in_sizes[2] / DIM;
    const int N_ = NU + NI;

    // workspace layout (16B-aligned chunks)
    char* p = (char*)d_ws;
    int2* edges = (int2*)p;                        p += align16((size_t)E_ * 8);
    __hip_bfloat16* h = (__hip_bfloat16*)p;        p += align16((size_t)N_ * DIM * 2);
    float* t1   = (float*)p;                       p += align16((size_t)N_ * DIM * 4);
    float* dinv = (float*)p;                       p += align16((size_t)N_ * 4);
    int* cnt    = (int*)p;                         p += align16((size_t)N_ * 4);
    int* rowptr = (int*)p;                         p += align16((size_t)(N_ + 1) * 4);
    int* cursor = (int*)p;                         p += align16((size_t)N_ * 4);
    int* partial = (int*)p;                        p += align16(1024 * 4);

    int nb = (N_ + 255) / 256;

    zero_cnt_kernel<<<(N_ + 255) / 256, 256, 0, stream>>>(cnt, N_);
    count_kernel<<<(E_ + 255) / 256, 256, 0, stream>>>(ei, cnt, E_);
    scanA_kernel<<<nb, 256, 0, stream>>>(cnt, rowptr, partial, N_);
    scanB_kernel<<<1, 1024, 0, stream>>>(partial, nb);
    scanC_kernel<<<(N_ + 255) / 256, 256, 0, stream>>>(cnt, rowptr, cursor, dinv,
                                                       partial, N_, E_);
    fill_kernel<<<(E_ + 255) / 256, 256, 0, stream>>>(ei, dinv, cursor, edges, E_);

    int waves = (N_ + 31) / 32;
    int gblocks = (waves + 3) / 4;
    int ablocks = (N_ + 3) / 4;

    // layer 1
    gemm_fused_kernel<<<gblocks, 256, 0, stream>>>(user_emb, item_emb, NU,
                                                   W1, b1, dinv, h, t1, N_);
    agg_kernel<<<ablocks, 256, 0, stream>>>(rowptr, edges, h, t1, N_);
    // layer 2
    gemm_fused_kernel<<<gblocks, 256, 0, stream>>>(t1, t1, N_,
                                                   W2, b2, dinv, h, out, N_);
    agg_kernel<<<ablocks, 256, 0, stream>>>(rowptr, edges, h, out, N_);
}

// Round 5
// 406.855 us; speedup vs baseline: 2.0439x; 1.1593x over previous
//
#include <hip/hip_runtime.h>

#define DIM 64
#define GPW 4   // 16-row groups per wave in gemm

typedef __attribute__((ext_vector_type(8))) __bf16 bf16x8;
typedef __attribute__((ext_vector_type(4))) float f32x4;

__device__ __forceinline__ f32x4 mfma16(bf16x8 a, bf16x8 b, f32x4 c) {
    return __builtin_amdgcn_mfma_f32_16x16x32_bf16(a, b, c, 0, 0, 0);
}

// ---------- CSR build ----------

__global__ void zero_cnt_kernel(int* __restrict__ cnt, int n) {
    int i = blockIdx.x * blockDim.x + threadIdx.x;
    if (i < n) cnt[i] = 0;
}

__global__ void count_kernel(const int* __restrict__ ei, int* __restrict__ cnt, int E_) {
    int e = blockIdx.x * blockDim.x + threadIdx.x;
    if (e < E_) atomicAdd(&cnt[ei[E_ + e]], 1);
}

__global__ __launch_bounds__(256) void scanA_kernel(const int* __restrict__ cnt,
                                                    int* __restrict__ rowptr,
                                                    int* __restrict__ partial, int n) {
    __shared__ int sm[256];
    int tid = threadIdx.x;
    int i = blockIdx.x * 256 + tid;
    int v = (i < n) ? cnt[i] : 0;
    sm[tid] = v;
    __syncthreads();
    for (int off = 1; off < 256; off <<= 1) {
        int t = 0;
        if (tid >= off) t = sm[tid - off];
        __syncthreads();
        if (tid >= off) sm[tid] += t;
        __syncthreads();
    }
    if (i < n) rowptr[i] = sm[tid] - v;
    if (tid == 255) partial[blockIdx.x] = sm[255];
}

__global__ __launch_bounds__(1024) void scanB_kernel(int* __restrict__ partial, int nb) {
    __shared__ int sm[1024];
    int tid = threadIdx.x;
    int v = (tid < nb) ? partial[tid] : 0;
    sm[tid] = v;
    __syncthreads();
    for (int off = 1; off < 1024; off <<= 1) {
        int t = 0;
        if (tid >= off) t = sm[tid - off];
        __syncthreads();
        if (tid >= off) sm[tid] += t;
        __syncthreads();
    }
    if (tid < nb) partial[tid] = sm[tid] - v;
}

__global__ void scanC_kernel(const int* __restrict__ cnt, int* __restrict__ rowptr,
                             int* __restrict__ cursor, float* __restrict__ dinv,
                             const int* __restrict__ partial, int n, int E_) {
    int i = blockIdx.x * blockDim.x + threadIdx.x;
    if (i < n) {
        int val = rowptr[i] + partial[i >> 8];
        rowptr[i] = val;
        cursor[i] = val;
        dinv[i] = rsqrtf((float)(1 + cnt[i]));
    }
    if (i == 0) rowptr[n] = E_;
}

// scatter src indices into CSR buckets (weights folded into h', so 4 B/edge)
__global__ void fill_kernel(const int* __restrict__ ei, int* __restrict__ cursor,
                            int* __restrict__ srcs, int E_) {
    int e = blockIdx.x * blockDim.x + threadIdx.x;
    if (e >= E_) return;
    int s = ei[e], d = ei[E_ + e];
    int pos = atomicAdd(&cursor[d], 1);
    srcs[pos] = s;
}

// ---------- layer kernels ----------

// h'(bf16) = (x @ W) * dinv[row].   MFMA 16x16x32 bf16.
// A: lane holds A[m=lane&15][k=quad*8+j]; B: W[k=quad*8+j][n=lane&15];
// D: row=quad*4+reg, col=lane&15  (per guide §3, m89/m91-verified layouts).
template <bool BF16IN>
__global__ __launch_bounds__(256) void gemm_kernel(
    const void* __restrict__ xa_, const void* __restrict__ xb_, int split,
    const float* __restrict__ W, const float* __restrict__ dinv,
    __bf16* __restrict__ h, int n, int ngroups) {
    int lane = threadIdx.x & 63;
    int q = lane >> 4, t = lane & 15;
    int wv = __builtin_amdgcn_readfirstlane(threadIdx.x >> 6);
    int g0 = (blockIdx.x * 4 + wv) * GPW;
    if (g0 >= ngroups) return;

    // W fragments (8): stride-64 gathers, L1-hot 16 KB
    bf16x8 Bf[4][2];
#pragma unroll
    for (int nt = 0; nt < 4; ++nt)
#pragma unroll
        for (int kt = 0; kt < 2; ++kt) {
            bf16x8 f;
#pragma unroll
            for (int j = 0; j < 8; ++j)
                f[j] = (__bf16)W[(kt * 32 + q * 8 + j) * DIM + nt * 16 + t];
            Bf[nt][kt] = f;
        }

    auto loadA = [&](int r0, f32x4* raw) {
        int row = r0 + t;
        if (row >= n) row = n - 1;
        if constexpr (BF16IN) {
            const __bf16* xr = (const __bf16*)xa_ + (size_t)row * DIM;
            raw[0] = *(const f32x4*)(xr + q * 8);
            raw[1] = *(const f32x4*)(xr + 32 + q * 8);
        } else {
            const float* xr = (row < split)
                ? ((const float*)xa_ + (size_t)row * DIM)
                : ((const float*)xb_ + (size_t)(row - split) * DIM);
            raw[0] = *(const f32x4*)(xr + q * 8);
            raw[1] = *(const f32x4*)(xr + q * 8 + 4);
            raw[2] = *(const f32x4*)(xr + 32 + q * 8);
            raw[3] = *(const f32x4*)(xr + 32 + q * 8 + 4);
        }
    };

    f32x4 cur[4];
    loadA(g0 * 16, cur);

#pragma unroll 1
    for (int gi = 0; gi < GPW; ++gi) {
        int g = g0 + gi;
        if (g >= ngroups) break;
        int r0 = g * 16;
        f32x4 nxt[4];
        bool pf = (gi + 1 < GPW) && (g + 1 < ngroups);
        if (pf) loadA(r0 + 16, nxt);

        bf16x8 A0, A1;
        if constexpr (BF16IN) {
            A0 = __builtin_bit_cast(bf16x8, cur[0]);
            A1 = __builtin_bit_cast(bf16x8, cur[1]);
        } else {
#pragma unroll
            for (int j = 0; j < 4; ++j) {
                A0[j] = (__bf16)cur[0][j]; A0[j + 4] = (__bf16)cur[1][j];
                A1[j] = (__bf16)cur[2][j]; A1[j + 4] = (__bf16)cur[3][j];
            }
        }

        f32x4 z = {0.f, 0.f, 0.f, 0.f};
        f32x4 acc[4];
#pragma unroll
        for (int nt = 0; nt < 4; ++nt)
            acc[nt] = mfma16(A1, Bf[nt][1], mfma16(A0, Bf[nt][0], z));

        f32x4 d4 = *(const f32x4*)(dinv + r0 + q * 4);
#pragma unroll
        for (int nt = 0; nt < 4; ++nt)
#pragma unroll
            for (int reg = 0; reg < 4; ++reg) {
                int row = r0 + q * 4 + reg;
                if (row < n)
                    h[(size_t)row * DIM + nt * 16 + t] =
                        (__bf16)(acc[nt][reg] * d4[reg]);
            }
#pragma unroll
        for (int i = 0; i < 4; ++i) cur[i] = nxt[i];
    }
}

// out[node] = b + dinv[node] * (h'[node] + sum_s h'[s])
template <typename OutT>
__global__ __launch_bounds__(256) void agg_kernel(
    const int* __restrict__ rowptr, const int* __restrict__ srcs,
    const __bf16* __restrict__ h, const float* __restrict__ bias,
    const float* __restrict__ dinv, OutT* __restrict__ out, int n) {
    int lane = threadIdx.x & 63;
    int node = blockIdx.x * 4 + __builtin_amdgcn_readfirstlane(threadIdx.x >> 6);
    if (node >= n) return;
    int beg = rowptr[node], end = rowptr[node + 1];
    float acc = (float)h[(size_t)node * DIM + lane];   // self-loop row, coalesced
    float a0 = 0.f, a1 = 0.f, a2 = 0.f, a3 = 0.f;
    int i = beg;
    for (; i + 4 <= end; i += 4) {
        int s0 = srcs[i], s1 = srcs[i + 1], s2 = srcs[i + 2], s3 = srcs[i + 3];
        a0 += (float)h[(size_t)s0 * DIM + lane];
        a1 += (float)h[(size_t)s1 * DIM + lane];
        a2 += (float)h[(size_t)s2 * DIM + lane];
        a3 += (float)h[(size_t)s3 * DIM + lane];
    }
    for (; i < end; ++i)
        acc += (float)h[(size_t)srcs[i] * DIM + lane];
    acc += (a0 + a1) + (a2 + a3);
    float res = fmaf(dinv[node], acc, bias[lane]);
    out[(size_t)node * DIM + lane] = (OutT)res;
}

static inline size_t align16(size_t x) { return (x + 15) & ~(size_t)15; }

extern "C" void kernel_launch(void* const* d_in, const int* in_sizes, int n_in,
                              void* d_out, int out_size, void* d_ws, size_t ws_size,
                              hipStream_t stream) {
    const int* ei         = (const int*)d_in[0];
    const float* user_emb = (const float*)d_in[1];
    const float* item_emb = (const float*)d_in[2];
    const float* W1 = (const float*)d_in[3];
    const float* b1 = (const float*)d_in[4];
    const float* W2 = (const float*)d_in[5];
    const float* b2 = (const float*)d_in[6];
    float* out = (float*)d_out;

    const int E_ = in_sizes[0] / 2;
    const int NU = in_sizes[1] / DIM;
    const int NI = in_sizes[2] / DIM;
    const int N_ = NU + NI;

    // workspace layout (16B-aligned)
    char* p = (char*)d_ws;
    int* srcs = (int*)p;                     p += align16((size_t)E_ * 4);
    __bf16* h  = (__bf16*)p;                 p += align16((size_t)N_ * DIM * 2);
    __bf16* t1 = (__bf16*)p;                 p += align16((size_t)N_ * DIM * 2);
    float* dinv = (float*)p;                 p += align16((size_t)N_ * 4);
    int* cnt    = (int*)p;                   p += align16((size_t)N_ * 4);
    int* rowptr = (int*)p;                   p += align16((size_t)(N_ + 1) * 4);
    int* cursor = (int*)p;                   p += align16((size_t)N_ * 4);
    int* partial = (int*)p;                  p += align16(1024 * 4);

    int nb = (N_ + 255) / 256;

    zero_cnt_kernel<<<(N_ + 255) / 256, 256, 0, stream>>>(cnt, N_);
    count_kernel<<<(E_ + 255) / 256, 256, 0, stream>>>(ei, cnt, E_);
    scanA_kernel<<<nb, 256, 0, stream>>>(cnt, rowptr, partial, N_);
    scanB_kernel<<<1, 1024, 0, stream>>>(partial, nb);
    scanC_kernel<<<(N_ + 255) / 256, 256, 0, stream>>>(cnt, rowptr, cursor, dinv,
                                                       partial, N_, E_);
    fill_kernel<<<(E_ + 255) / 256, 256, 0, stream>>>(ei, cursor, srcs, E_);

    int NG = (N_ + 15) / 16;                       // 16-row groups
    int gblocks = (NG + 4 * GPW - 1) / (4 * GPW);  // 4 waves/block
    int ablocks = (N_ + 3) / 4;

    // layer 1
    gemm_kernel<false><<<gblocks, 256, 0, stream>>>(user_emb, item_emb, NU,
                                                    W1, dinv, h, N_, NG);
    agg_kernel<__bf16><<<ablocks, 256, 0, stream>>>(rowptr, srcs, h, b1, dinv, t1, N_);
    // layer 2
    gemm_kernel<true><<<gblocks, 256, 0, stream>>>(t1, t1, N_,
                                                   W2, dinv, h, N_, NG);
    agg_kernel<float><<<ablocks, 256, 0, stream>>>(rowptr, srcs, h, b2, dinv, out, N_);
}